// Round 4
// baseline (587.924 us; speedup 1.0000x reference)
//
#include <hip/hip_runtime.h>
#include <hip/hip_fp16.h>

typedef _Float16 f16;
typedef _Float16 f16x8 __attribute__((ext_vector_type(8)));
typedef float f32x4 __attribute__((ext_vector_type(4)));

#define MFMA(a,b,c) __builtin_amdgcn_mfma_f32_16x16x32_f16((a),(b),(c),0,0,0)

// B=16384, IN=512, HID=1024, OUT=512, E=16, K=4
// ws: w1fr 16MB + w2fr 16MB + routing ~2.6MB = ~34.6MB

// w1: [16][512][1024] -> fragment layout: frag fid=((e*64+n0)*16+kc), lane l, elem i
//   = w1[e][kc*32+(l>>4)*8+i][n0*16+(l&15)]
__global__ void k_cvt_w1(const float* __restrict__ w1, f16* __restrict__ w1fr) {
  int fid = blockIdx.x * 4 + (threadIdx.x >> 6);
  int l = threadIdx.x & 63;
  int e = fid >> 10, n0 = (fid >> 4) & 63, kc = fid & 15;
  int kbase = kc * 32 + (l >> 4) * 8;
  int col = n0 * 16 + (l & 15);
  const float* src = w1 + ((size_t)e * 512 + kbase) * 1024 + col;
  f16x8 o;
  #pragma unroll
  for (int i = 0; i < 8; i++) o[i] = (f16)src[(size_t)i * 1024];
  *(f16x8*)(w1fr + (size_t)fid * 512 + l * 8) = o;
}

// w2: [16][1024][512] -> frag fid=((e*32+n0)*32+kc)
__global__ void k_cvt_w2(const float* __restrict__ w2, f16* __restrict__ w2fr) {
  int fid = blockIdx.x * 4 + (threadIdx.x >> 6);
  int l = threadIdx.x & 63;
  int e = fid >> 10, n0 = (fid >> 5) & 31, kc = fid & 31;
  int kbase = kc * 32 + (l >> 4) * 8;
  int col = n0 * 16 + (l & 15);
  const float* src = w2 + ((size_t)e * 1024 + kbase) * 512 + col;
  f16x8 o;
  #pragma unroll
  for (int i = 0; i < 8; i++) o[i] = (f16)src[(size_t)i * 512];
  *(f16x8*)(w2fr + (size_t)fid * 512 + l * 8) = o;
}

// ---------------- gating ----------------
__global__ void k_gate(const float* __restrict__ x, const float* __restrict__ wg,
                       int* __restrict__ tk_idx, float* __restrict__ tk_gate) {
  int w = threadIdx.x >> 6, l = threadIdx.x & 63;
  int r = blockIdx.x * 4 + w;
  float p[16];
  #pragma unroll
  for (int e = 0; e < 16; e++) p[e] = 0.f;
  const float* xr = x + (size_t)r * 512;
  #pragma unroll
  for (int t = 0; t < 8; t++) {
    float xv = xr[t * 64 + l];
    const float* wrow = wg + (t * 64 + l) * 16;
    #pragma unroll
    for (int e = 0; e < 16; e++) p[e] += xv * wrow[e];
  }
  #pragma unroll
  for (int e = 0; e < 16; e++) {
    float v = p[e];
    #pragma unroll
    for (int m = 32; m >= 1; m >>= 1) v += __shfl_xor(v, m);
    p[e] = v;
  }
  unsigned chosen = 0;
  float bv[4]; int bi[4];
  #pragma unroll
  for (int j = 0; j < 4; j++) {
    float best = -3.4e38f; int be = 0;
    #pragma unroll
    for (int e = 0; e < 16; e++) {
      bool ok = !((chosen >> e) & 1u) && (p[e] > best);
      if (ok) { best = p[e]; be = e; }
    }
    chosen |= 1u << be; bv[j] = best; bi[j] = be;
  }
  float m0 = bv[0];
  float e0 = __expf(bv[0] - m0), e1 = __expf(bv[1] - m0),
        e2 = __expf(bv[2] - m0), e3 = __expf(bv[3] - m0);
  float s = e0 + e1 + e2 + e3;
  if (l == 0) {
    *(int4*)(tk_idx + (size_t)r * 4) = make_int4(bi[0], bi[1], bi[2], bi[3]);
    *(float4*)(tk_gate + (size_t)r * 4) = make_float4(e0 / s, e1 / s, e2 / s, e3 / s);
  }
}

// ---------------- routing (deterministic compaction) ----------------
__global__ void k_route_count(const int* __restrict__ tk_idx, int* __restrict__ partial) {
  int e = blockIdx.x >> 6, chunk = blockIdx.x & 63;
  int t = threadIdx.x;
  int row = chunk * 256 + t;
  int4 tk = ((const int4*)tk_idx)[row];
  bool match = (tk.x == e) || (tk.y == e) || (tk.z == e) || (tk.w == e);
  unsigned long long m = __ballot(match);
  __shared__ int wc[4];
  if ((t & 63) == 0) wc[t >> 6] = (int)__popcll(m);
  __syncthreads();
  if (t == 0) partial[e * 64 + chunk] = wc[0] + wc[1] + wc[2] + wc[3];
}

__global__ void k_route_scan(const int* __restrict__ partial, int* __restrict__ chunk_base,
                             int* __restrict__ count) {
  int l = threadIdx.x; // 64 threads
  for (int e = 0; e < 16; e++) {
    int v = partial[e * 64 + l];
    int orig = v;
    #pragma unroll
    for (int off = 1; off < 64; off <<= 1) {
      int u = __shfl_up(v, off);
      if (l >= off) v += u;
    }
    chunk_base[e * 64 + l] = v - orig;
    if (l == 63) count[e] = v;
  }
}

__global__ void k_route_scatter(const int* __restrict__ tk_idx, const float* __restrict__ tk_gate,
                                const int* __restrict__ chunk_base, int* __restrict__ rows_pk,
                                float* __restrict__ gates_l) {
  int e = blockIdx.x >> 6, chunk = blockIdx.x & 63;
  int t = threadIdx.x, w = t >> 6, l = t & 63;
  int row = chunk * 256 + t;
  int4 tk = ((const int4*)tk_idx)[row];
  int j = (tk.x == e) ? 0 : (tk.y == e) ? 1 : (tk.z == e) ? 2 : (tk.w == e) ? 3 : -1;
  bool match = (j >= 0);
  unsigned long long m = __ballot(match);
  __shared__ int wc[4];
  if (l == 0) wc[w] = (int)__popcll(m);
  __syncthreads();
  int wbase = 0;
  #pragma unroll
  for (int i = 0; i < 4; i++) if (i < w) wbase += wc[i];
  if (match) {
    int pos = (int)__popcll(m & ((1ULL << l) - 1ULL));
    int idx = e * 16384 + chunk_base[e * 64 + chunk] + wbase + pos;
    rows_pk[idx] = row | (j << 16);
    gates_l[idx] = tk_gate[(size_t)row * 4 + j];
  }
}

// ---------------- zero output ----------------
__global__ void k_zero(float4* __restrict__ y4) {
  y4[blockIdx.x * 256 + threadIdx.x] = make_float4(0.f, 0.f, 0.f, 0.f);
}

// ---------------- fused expert FFN (fp16 MFMA, h-chunked, XCD-pinned) ----------------
// grid 8192; remap so XCD x serves experts {2x, 2x+1} (weights 4MB = L2-resident).
// 32 rows/block, 4 waves; LDS ~49KB -> 3 blocks/CU (12 waves/CU).
__global__ __launch_bounds__(256, 3) void k_expert(
    const float* __restrict__ x, const f16* __restrict__ w1fr, const f16* __restrict__ w2fr,
    const float* __restrict__ b1, const float* __restrict__ b2,
    const int* __restrict__ count, const int* __restrict__ rows_pk,
    const float* __restrict__ gates_l, float* __restrict__ y)
{
  int p = blockIdx.x;
  int xcd = p & 7, slot = p >> 3;
  int e = (xcd << 1) | (slot >> 9);
  int rb = slot & 511;
  int cnt = count[e];
  int mstart = rb * 32;
  if (mstart >= cnt) return;
  int nvalid = cnt - mstart; if (nvalid > 32) nvalid = 32;

  __shared__ f16 a_lds[32 * 512];    // 32KB x fp16, swizzled byte^=(row&7)<<4
  __shared__ f16 h_lds[32 * 256];    // 16KB h chunk, swizzled
  __shared__ int rowarr[32];
  __shared__ float gatearr[32];
  __shared__ float red[2][4][32];

  int t = threadIdx.x, w = t >> 6, l = t & 63;
  int lq = l >> 4, lr = l & 15;

  if (t < 32) {
    int src = e * 16384 + mstart + ((t < nvalid) ? t : 0);
    rowarr[t] = rows_pk[src];
    gatearr[t] = gates_l[src];
  }
  __syncthreads();

  // ---- stage x once: gather f32 -> cvt -> a_lds fp16 ----
  {
    int r = t >> 3, s0 = t & 7;
    int xr = rowarr[r] & 0xFFFF;
    const float* sp = x + (size_t)xr * 512;
    #pragma unroll
    for (int j = 0; j < 8; j++) {
      int seg = s0 + j * 8;
      float4 u0 = *(const float4*)(sp + seg * 8);
      float4 u1 = *(const float4*)(sp + seg * 8 + 4);
      f16x8 v;
      v[0] = (f16)u0.x; v[1] = (f16)u0.y; v[2] = (f16)u0.z; v[3] = (f16)u0.w;
      v[4] = (f16)u1.x; v[5] = (f16)u1.y; v[6] = (f16)u1.z; v[7] = (f16)u1.w;
      int byte = (r * 1024 + seg * 16) ^ ((r & 7) << 4);
      *(f16x8*)((char*)a_lds + byte) = v;
    }
  }
  __syncthreads();

  const f16x8* w1f8 = (const f16x8*)w1fr;
  const f16x8* w2f8 = (const f16x8*)w2fr;
  // per-lane fragment bases (wave owns N-quarter)
  const f16x8* base1 = w1f8 + (size_t)((e * 64 + w * 4) * 16) * 64 + l;  // + (hc*16+n0)*1024 + kcg*64
  const f16x8* base2 = w2f8 + (size_t)((e * 32 + w * 8) * 32) * 64 + l;  // + n0*2048 + (hc*8+kc2)*64

  f32x4 acc2[2][8];
  #pragma unroll
  for (int a = 0; a < 2; a++)
    #pragma unroll
    for (int b = 0; b < 8; b++)
      #pragma unroll
      for (int q = 0; q < 4; q++) acc2[a][b][q] = 0.f;

  #pragma unroll 1
  for (int hc = 0; hc < 4; hc++) {
    // ---- stage 1 partial: h[:, hc*256 .. +256) = relu(x @ w1 + b1), K=512 ----
    f32x4 acc1[2][4];
    #pragma unroll
    for (int a = 0; a < 2; a++)
      #pragma unroll
      for (int b = 0; b < 4; b++)
        #pragma unroll
        for (int q = 0; q < 4; q++) acc1[a][b][q] = 0.f;

    const f16x8* bp1 = base1 + (size_t)hc * 16 * 1024;
    f16x8 bfa[4], bfb[4];
    #pragma unroll
    for (int n0 = 0; n0 < 4; n0++) bfa[n0] = bp1[n0 * 1024];
    #pragma unroll
    for (int kcg = 0; kcg < 16; kcg += 2) {
      #pragma unroll
      for (int n0 = 0; n0 < 4; n0++) bfb[n0] = bp1[n0 * 1024 + (kcg + 1) * 64];
      {
        int byte0 = (lr * 1024 + kcg * 64 + lq * 16) ^ ((lr & 7) << 4);
        f16x8 a0 = *(const f16x8*)((char*)a_lds + byte0);
        f16x8 a1 = *(const f16x8*)((char*)a_lds + byte0 + 16 * 1024);
        #pragma unroll
        for (int n0 = 0; n0 < 4; n0++) {
          acc1[0][n0] = MFMA(a0, bfa[n0], acc1[0][n0]);
          acc1[1][n0] = MFMA(a1, bfa[n0], acc1[1][n0]);
        }
      }
      if (kcg + 2 < 16) {
        #pragma unroll
        for (int n0 = 0; n0 < 4; n0++) bfa[n0] = bp1[n0 * 1024 + (kcg + 2) * 64];
      }
      {
        int byte0 = (lr * 1024 + (kcg + 1) * 64 + lq * 16) ^ ((lr & 7) << 4);
        f16x8 a0 = *(const f16x8*)((char*)a_lds + byte0);
        f16x8 a1 = *(const f16x8*)((char*)a_lds + byte0 + 16 * 1024);
        #pragma unroll
        for (int n0 = 0; n0 < 4; n0++) {
          acc1[0][n0] = MFMA(a0, bfb[n0], acc1[0][n0]);
          acc1[1][n0] = MFMA(a1, bfb[n0], acc1[1][n0]);
        }
      }
    }

    __syncthreads();   // previous chunk's h fully consumed
    // epilogue: bias + relu -> h_lds
    #pragma unroll
    for (int n0 = 0; n0 < 4; n0++) {
      int colc = (w * 4 + n0) * 16 + lr;
      float bv = b1[e * 1024 + hc * 256 + colc];
      #pragma unroll
      for (int m0 = 0; m0 < 2; m0++)
        #pragma unroll
        for (int q = 0; q < 4; q++) {
          int row = m0 * 16 + lq * 4 + q;
          float hv = fmaxf(acc1[m0][n0][q] + bv, 0.f);
          int byte = (row * 512 + colc * 2) ^ ((row & 7) << 4);
          *(f16*)((char*)h_lds + byte) = (f16)hv;
        }
    }
    __syncthreads();

    // ---- stage 2 partial: acc2 += h_chunk @ w2[hc*256.., :], K=256 ----
    const f16x8* bp2 = base2 + (size_t)hc * 8 * 64;
    f16x8 wfa[8], wfb[8];
    #pragma unroll
    for (int n0 = 0; n0 < 8; n0++) wfa[n0] = bp2[n0 * 2048];
    #pragma unroll
    for (int kc2 = 0; kc2 < 8; kc2 += 2) {
      #pragma unroll
      for (int n0 = 0; n0 < 8; n0++) wfb[n0] = bp2[n0 * 2048 + (kc2 + 1) * 64];
      {
        int byte0 = (lr * 512 + kc2 * 64 + lq * 16) ^ ((lr & 7) << 4);
        f16x8 h0 = *(const f16x8*)((char*)h_lds + byte0);
        f16x8 h1 = *(const f16x8*)((char*)h_lds + byte0 + 16 * 512);
        #pragma unroll
        for (int n0 = 0; n0 < 8; n0++) {
          acc2[0][n0] = MFMA(h0, wfa[n0], acc2[0][n0]);
          acc2[1][n0] = MFMA(h1, wfa[n0], acc2[1][n0]);
        }
      }
      if (kc2 + 2 < 8) {
        #pragma unroll
        for (int n0 = 0; n0 < 8; n0++) wfa[n0] = bp2[n0 * 2048 + (kc2 + 2) * 64];
      }
      {
        int byte0 = (lr * 512 + (kc2 + 1) * 64 + lq * 16) ^ ((lr & 7) << 4);
        f16x8 h0 = *(const f16x8*)((char*)h_lds + byte0);
        f16x8 h1 = *(const f16x8*)((char*)h_lds + byte0 + 16 * 512);
        #pragma unroll
        for (int n0 = 0; n0 < 8; n0++) {
          acc2[0][n0] = MFMA(h0, wfb[n0], acc2[0][n0]);
          acc2[1][n0] = MFMA(h1, wfb[n0], acc2[1][n0]);
        }
      }
    }
  }

  // bias2
  #pragma unroll
  for (int n0 = 0; n0 < 8; n0++) {
    float bv = b2[e * 512 + (w * 8 + n0) * 16 + lr];
    #pragma unroll
    for (int m0 = 0; m0 < 2; m0++)
      #pragma unroll
      for (int q = 0; q < 4; q++) acc2[m0][n0][q] += bv;
  }

  // ---- softmax across full row (512 cols over 4 waves) ----
  float rmax[2][4];
  #pragma unroll
  for (int m0 = 0; m0 < 2; m0++)
    #pragma unroll
    for (int q = 0; q < 4; q++) {
      float v = acc2[m0][0][q];
      #pragma unroll
      for (int n0 = 1; n0 < 8; n0++) v = fmaxf(v, acc2[m0][n0][q]);
      #pragma unroll
      for (int m = 1; m < 16; m <<= 1) v = fmaxf(v, __shfl_xor(v, m));
      rmax[m0][q] = v;
    }
  if (lr == 0) {
    #pragma unroll
    for (int m0 = 0; m0 < 2; m0++)
      #pragma unroll
      for (int q = 0; q < 4; q++) red[0][w][m0 * 16 + lq * 4 + q] = rmax[m0][q];
  }
  __syncthreads();
  float gmax[2][4];
  #pragma unroll
  for (int m0 = 0; m0 < 2; m0++)
    #pragma unroll
    for (int q = 0; q < 4; q++) {
      int row = m0 * 16 + lq * 4 + q;
      gmax[m0][q] = fmaxf(fmaxf(red[0][0][row], red[0][1][row]),
                          fmaxf(red[0][2][row], red[0][3][row]));
    }
  float psum[2][4];
  #pragma unroll
  for (int m0 = 0; m0 < 2; m0++)
    #pragma unroll
    for (int q = 0; q < 4; q++) psum[m0][q] = 0.f;
  #pragma unroll
  for (int m0 = 0; m0 < 2; m0++)
    #pragma unroll
    for (int n0 = 0; n0 < 8; n0++)
      #pragma unroll
      for (int q = 0; q < 4; q++) {
        float pp = __expf(acc2[m0][n0][q] - gmax[m0][q]);
        acc2[m0][n0][q] = pp;
        psum[m0][q] += pp;
      }
  #pragma unroll
  for (int m0 = 0; m0 < 2; m0++)
    #pragma unroll
    for (int q = 0; q < 4; q++) {
      float v = psum[m0][q];
      #pragma unroll
      for (int m = 1; m < 16; m <<= 1) v += __shfl_xor(v, m);
      psum[m0][q] = v;
    }
  if (lr == 0) {
    #pragma unroll
    for (int m0 = 0; m0 < 2; m0++)
      #pragma unroll
      for (int q = 0; q < 4; q++) red[1][w][m0 * 16 + lq * 4 + q] = psum[m0][q];
  }
  __syncthreads();

  // ---- gated atomic accumulate into y ----
  #pragma unroll
  for (int m0 = 0; m0 < 2; m0++) {
    #pragma unroll
    for (int q = 0; q < 4; q++) {
      int row = m0 * 16 + lq * 4 + q;
      if (row < nvalid) {
        float s = red[1][0][row] + red[1][1][row] + red[1][2][row] + red[1][3][row];
        float sc = gatearr[row] / s;
        int orow = rowarr[row] & 0xFFFF;
        float* yr = y + (size_t)orow * 512;
        #pragma unroll
        for (int n0 = 0; n0 < 8; n0++) {
          int colo = (w * 8 + n0) * 16 + lr;
          atomicAdd(yr + colo, acc2[m0][n0][q] * sc);
        }
      }
    }
  }
}

// ---------------- launch ----------------
extern "C" void kernel_launch(void* const* d_in, const int* in_sizes, int n_in,
                              void* d_out, int out_size, void* d_ws, size_t ws_size,
                              hipStream_t stream) {
  (void)in_sizes; (void)n_in; (void)out_size; (void)ws_size;
  const float* x  = (const float*)d_in[0];
  const float* wg = (const float*)d_in[1];
  const float* w1 = (const float*)d_in[2];
  const float* b1 = (const float*)d_in[3];
  const float* w2 = (const float*)d_in[4];
  const float* b2 = (const float*)d_in[5];
  float* y = (float*)d_out;

  char* ws = (char*)d_ws;
  size_t off = 0;
  auto alloc = [&](size_t bytes) -> char* {
    char* p = ws + off;
    off += (bytes + 255) & ~(size_t)255;
    return p;
  };
  f16*   w1fr       = (f16*)  alloc((size_t)16 * 512 * 1024 * 2);
  f16*   w2fr       = (f16*)  alloc((size_t)16 * 1024 * 512 * 2);
  int*   tk_idx     = (int*)  alloc((size_t)16384 * 4 * 4);
  float* tk_gate    = (float*)alloc((size_t)16384 * 4 * 4);
  int*   rows_pk    = (int*)  alloc((size_t)16 * 16384 * 4);
  float* gates_l    = (float*)alloc((size_t)16 * 16384 * 4);
  int*   partial    = (int*)  alloc(16 * 64 * 4);
  int*   chunk_base = (int*)  alloc(16 * 64 * 4);
  int*   count      = (int*)  alloc(256);
  // total ~34.6 MB

  k_cvt_w1<<<dim3(4096), dim3(256), 0, stream>>>(w1, w1fr);
  k_cvt_w2<<<dim3(4096), dim3(256), 0, stream>>>(w2, w2fr);
  k_gate<<<dim3(4096), dim3(256), 0, stream>>>(x, wg, tk_idx, tk_gate);
  k_route_count<<<dim3(1024), dim3(256), 0, stream>>>(tk_idx, partial);
  k_route_scan<<<dim3(1), dim3(64), 0, stream>>>(partial, chunk_base, count);
  k_route_scatter<<<dim3(1024), dim3(256), 0, stream>>>(tk_idx, tk_gate, chunk_base,
                                                        rows_pk, gates_l);
  k_zero<<<dim3(8192), dim3(256), 0, stream>>>((float4*)y);
  k_expert<<<dim3(16 * 512), dim3(256), 0, stream>>>(x, w1fr, w2fr, b1, b2,
                                                     count, rows_pk, gates_l, y);
}

// Round 5
// 438.749 us; speedup vs baseline: 1.3400x; 1.3400x over previous
//
#include <hip/hip_runtime.h>
#include <hip/hip_fp16.h>

typedef _Float16 f16;
typedef _Float16 f16x8 __attribute__((ext_vector_type(8)));
typedef float f32x4 __attribute__((ext_vector_type(4)));

#define MFMA(a,b,c) __builtin_amdgcn_mfma_f32_16x16x32_f16((a),(b),(c),0,0,0)

// B=16384, IN=512, HID=1024, OUT=512, E=16, K=4
// ws: w1fr 16MB + w2fr 16MB + routing ~2.6MB = ~34.6MB (known-safe)

// w1: [16][512][1024] -> fragment fid=((e*64+n0)*16+kc), lane l, elem i
//   = w1[e][kc*32+(l>>4)*8+i][n0*16+(l&15)]
__global__ void k_cvt_w1(const float* __restrict__ w1, f16* __restrict__ w1fr) {
  int fid = blockIdx.x * 4 + (threadIdx.x >> 6);
  int l = threadIdx.x & 63;
  int e = fid >> 10, n0 = (fid >> 4) & 63, kc = fid & 15;
  int kbase = kc * 32 + (l >> 4) * 8;
  int col = n0 * 16 + (l & 15);
  const float* src = w1 + ((size_t)e * 512 + kbase) * 1024 + col;
  f16x8 o;
  #pragma unroll
  for (int i = 0; i < 8; i++) o[i] = (f16)src[(size_t)i * 1024];
  *(f16x8*)(w1fr + (size_t)fid * 512 + l * 8) = o;
}

// w2: [16][1024][512] -> frag fid=((e*32+n0)*32+kc)
__global__ void k_cvt_w2(const float* __restrict__ w2, f16* __restrict__ w2fr) {
  int fid = blockIdx.x * 4 + (threadIdx.x >> 6);
  int l = threadIdx.x & 63;
  int e = fid >> 10, n0 = (fid >> 5) & 31, kc = fid & 31;
  int kbase = kc * 32 + (l >> 4) * 8;
  int col = n0 * 16 + (l & 15);
  const float* src = w2 + ((size_t)e * 1024 + kbase) * 512 + col;
  f16x8 o;
  #pragma unroll
  for (int i = 0; i < 8; i++) o[i] = (f16)src[(size_t)i * 512];
  *(f16x8*)(w2fr + (size_t)fid * 512 + l * 8) = o;
}

// ---------------- gating ----------------
__global__ void k_gate(const float* __restrict__ x, const float* __restrict__ wg,
                       int* __restrict__ tk_idx, float* __restrict__ tk_gate) {
  int w = threadIdx.x >> 6, l = threadIdx.x & 63;
  int r = blockIdx.x * 4 + w;
  float p[16];
  #pragma unroll
  for (int e = 0; e < 16; e++) p[e] = 0.f;
  const float* xr = x + (size_t)r * 512;
  #pragma unroll
  for (int t = 0; t < 8; t++) {
    float xv = xr[t * 64 + l];
    const float* wrow = wg + (t * 64 + l) * 16;
    #pragma unroll
    for (int e = 0; e < 16; e++) p[e] += xv * wrow[e];
  }
  #pragma unroll
  for (int e = 0; e < 16; e++) {
    float v = p[e];
    #pragma unroll
    for (int m = 32; m >= 1; m >>= 1) v += __shfl_xor(v, m);
    p[e] = v;
  }
  unsigned chosen = 0;
  float bv[4]; int bi[4];
  #pragma unroll
  for (int j = 0; j < 4; j++) {
    float best = -3.4e38f; int be = 0;
    #pragma unroll
    for (int e = 0; e < 16; e++) {
      bool ok = !((chosen >> e) & 1u) && (p[e] > best);
      if (ok) { best = p[e]; be = e; }
    }
    chosen |= 1u << be; bv[j] = best; bi[j] = be;
  }
  float m0 = bv[0];
  float e0 = __expf(bv[0] - m0), e1 = __expf(bv[1] - m0),
        e2 = __expf(bv[2] - m0), e3 = __expf(bv[3] - m0);
  float s = e0 + e1 + e2 + e3;
  if (l == 0) {
    *(int4*)(tk_idx + (size_t)r * 4) = make_int4(bi[0], bi[1], bi[2], bi[3]);
    *(float4*)(tk_gate + (size_t)r * 4) = make_float4(e0 / s, e1 / s, e2 / s, e3 / s);
  }
}

// ---------------- routing (deterministic compaction) ----------------
__global__ void k_route_count(const int* __restrict__ tk_idx, int* __restrict__ partial) {
  int e = blockIdx.x >> 6, chunk = blockIdx.x & 63;
  int t = threadIdx.x;
  int row = chunk * 256 + t;
  int4 tk = ((const int4*)tk_idx)[row];
  bool match = (tk.x == e) || (tk.y == e) || (tk.z == e) || (tk.w == e);
  unsigned long long m = __ballot(match);
  __shared__ int wc[4];
  if ((t & 63) == 0) wc[t >> 6] = (int)__popcll(m);
  __syncthreads();
  if (t == 0) partial[e * 64 + chunk] = wc[0] + wc[1] + wc[2] + wc[3];
}

__global__ void k_route_scan(const int* __restrict__ partial, int* __restrict__ chunk_base,
                             int* __restrict__ count) {
  int l = threadIdx.x; // 64 threads
  for (int e = 0; e < 16; e++) {
    int v = partial[e * 64 + l];
    int orig = v;
    #pragma unroll
    for (int off = 1; off < 64; off <<= 1) {
      int u = __shfl_up(v, off);
      if (l >= off) v += u;
    }
    chunk_base[e * 64 + l] = v - orig;
    if (l == 63) count[e] = v;
  }
}

__global__ void k_route_scatter(const int* __restrict__ tk_idx, const float* __restrict__ tk_gate,
                                const int* __restrict__ chunk_base, int* __restrict__ rows_pk,
                                float* __restrict__ gates_l) {
  int e = blockIdx.x >> 6, chunk = blockIdx.x & 63;
  int t = threadIdx.x, w = t >> 6, l = t & 63;
  int row = chunk * 256 + t;
  int4 tk = ((const int4*)tk_idx)[row];
  int j = (tk.x == e) ? 0 : (tk.y == e) ? 1 : (tk.z == e) ? 2 : (tk.w == e) ? 3 : -1;
  bool match = (j >= 0);
  unsigned long long m = __ballot(match);
  __shared__ int wc[4];
  if (l == 0) wc[w] = (int)__popcll(m);
  __syncthreads();
  int wbase = 0;
  #pragma unroll
  for (int i = 0; i < 4; i++) if (i < w) wbase += wc[i];
  if (match) {
    int pos = (int)__popcll(m & ((1ULL << l) - 1ULL));
    int idx = e * 16384 + chunk_base[e * 64 + chunk] + wbase + pos;
    rows_pk[idx] = row | (j << 16);
    gates_l[idx] = tk_gate[(size_t)row * 4 + j];
  }
}

// ---------------- zero output ----------------
__global__ void k_zero(float4* __restrict__ y4) {
  y4[blockIdx.x * 256 + threadIdx.x] = make_float4(0.f, 0.f, 0.f, 0.f);
}

// ---------------- fused expert FFN: BM=64, 8 waves, duplicate-free N-split ----------------
// grid 4096; XCD pin: xcd=p&7 serves experts {2x,2x+1}. Each weight fragment
// loaded exactly ONCE per block (waves own distinct N-slices in both stages).
__global__ __launch_bounds__(512, 2) void k_expert(
    const float* __restrict__ x, const f16* __restrict__ w1fr, const f16* __restrict__ w2fr,
    const float* __restrict__ b1, const float* __restrict__ b2,
    const int* __restrict__ count, const int* __restrict__ rows_pk,
    const float* __restrict__ gates_l, float* __restrict__ y)
{
  int p = blockIdx.x;
  int xcd = p & 7, s = p >> 3;
  int e = (xcd << 1) | (s >> 8);
  int rb = s & 255;
  int cnt = count[e];
  int mstart = rb * 64;
  if (mstart >= cnt) return;
  int nvalid = cnt - mstart; if (nvalid > 64) nvalid = 64;

  __shared__ f16 x_lds[64 * 128];   // 16KB: x K-chunk, swizzled byte^=(row&7)<<4
  __shared__ f16 h_lds[64 * 256];   // 32KB: h chunk (256 cols), swizzled
  __shared__ int rowarr[64];
  __shared__ float gatearr[64];
  __shared__ float red[2][8][64];   // 4KB cross-wave softmax reduce

  int t = threadIdx.x, w = t >> 6, l = t & 63;
  int lq = l >> 4, lr = l & 15;

  if (t < 64) {
    int idx = (t < nvalid) ? t : (nvalid - 1);
    int src = e * 16384 + mstart + idx;
    rowarr[t] = rows_pk[src];
    gatearr[t] = gates_l[src];
  }
  __syncthreads();

  // staging assignment: 8 threads per row, 16 f32 each
  int srow = t >> 3, sc0 = (t & 7) * 16;
  const float* sp = x + (size_t)(rowarr[srow] & 0xFFFF) * 512 + sc0;

  const f16x8* w1f8 = (const f16x8*)w1fr;
  const f16x8* w2f8 = (const f16x8*)w2fr;

  f32x4 acc2[4][4];   // [mf][nf]: rows mf*16+lq*4+q, cols w*64+nf*16+lr
  #pragma unroll
  for (int a = 0; a < 4; a++)
    #pragma unroll
    for (int b = 0; b < 4; b++)
      #pragma unroll
      for (int q = 0; q < 4; q++) acc2[a][b][q] = 0.f;

  #pragma unroll 1
  for (int hc = 0; hc < 4; hc++) {
    // ---- stage 1 partial: h[:, hc*256 .. +256), K=512 in 4 x-chunks ----
    f32x4 acc1[4][2];  // [mf][nf]: cols w*32+nf*16+lr (of this 256 chunk)
    #pragma unroll
    for (int a = 0; a < 4; a++)
      #pragma unroll
      for (int b = 0; b < 2; b++)
        #pragma unroll
        for (int q = 0; q < 4; q++) acc1[a][b][q] = 0.f;

    #pragma unroll 1
    for (int kk = 0; kk < 4; kk++) {
      __syncthreads();  // previous x chunk (or prev hc's h) fully consumed
      {
        const float* qp = sp + kk * 128;
        float4 u0 = *(const float4*)(qp + 0);
        float4 u1 = *(const float4*)(qp + 4);
        float4 u2 = *(const float4*)(qp + 8);
        float4 u3 = *(const float4*)(qp + 12);
        f16x8 v0, v1;
        v0[0]=(f16)u0.x; v0[1]=(f16)u0.y; v0[2]=(f16)u0.z; v0[3]=(f16)u0.w;
        v0[4]=(f16)u1.x; v0[5]=(f16)u1.y; v0[6]=(f16)u1.z; v0[7]=(f16)u1.w;
        v1[0]=(f16)u2.x; v1[1]=(f16)u2.y; v1[2]=(f16)u2.z; v1[3]=(f16)u2.w;
        v1[4]=(f16)u3.x; v1[5]=(f16)u3.y; v1[6]=(f16)u3.z; v1[7]=(f16)u3.w;
        int b0 = (srow * 256 + sc0 * 2) ^ ((srow & 7) << 4);
        int b1b = (srow * 256 + sc0 * 2 + 16) ^ ((srow & 7) << 4);
        *(f16x8*)((char*)x_lds + b0) = v0;
        *(f16x8*)((char*)x_lds + b1b) = v1;
      }
      __syncthreads();

      // fragments: n0g = hc*16 + w*2 + nf ; kcg = kk*4 + k4
      const f16x8* bp1 = w1f8 + ((size_t)((e * 64 + hc * 16 + w * 2) * 16 + kk * 4)) * 64 + l;
      f16x8 bfa0 = bp1[0], bfa1 = bp1[16 * 64];
      #pragma unroll
      for (int k4 = 0; k4 < 4; k4++) {
        f16x8 bfb0, bfb1;
        if (k4 < 3) { bfb0 = bp1[(k4 + 1) * 64]; bfb1 = bp1[16 * 64 + (k4 + 1) * 64]; }
        f16x8 av[4];
        #pragma unroll
        for (int mf = 0; mf < 4; mf++) {
          int row = mf * 16 + lr;
          int byte = (row * 256 + k4 * 64 + lq * 16) ^ ((lr & 7) << 4);
          av[mf] = *(const f16x8*)((char*)x_lds + byte);
        }
        #pragma unroll
        for (int mf = 0; mf < 4; mf++) {
          acc1[mf][0] = MFMA(av[mf], bfa0, acc1[mf][0]);
          acc1[mf][1] = MFMA(av[mf], bfa1, acc1[mf][1]);
        }
        if (k4 < 3) { bfa0 = bfb0; bfa1 = bfb1; }
      }
    }

    // epilogue: bias + relu -> h_lds (h cols of this chunk)
    __syncthreads();
    #pragma unroll
    for (int nf = 0; nf < 2; nf++) {
      int col = w * 32 + nf * 16 + lr;
      float bv = b1[e * 1024 + hc * 256 + col];
      #pragma unroll
      for (int mf = 0; mf < 4; mf++)
        #pragma unroll
        for (int q = 0; q < 4; q++) {
          int row = mf * 16 + lq * 4 + q;
          float hv = fmaxf(acc1[mf][nf][q] + bv, 0.f);
          int byte = (row * 512 + col * 2) ^ ((row & 7) << 4);
          *(f16*)((char*)h_lds + byte) = (f16)hv;
        }
    }
    __syncthreads();

    // ---- stage 2 partial: acc2 += h_chunk @ w2[hc*256.., :], K=256 ----
    // n0g = w*4 + nf ; kc2g = hc*8 + kc2
    const f16x8* bp2 = w2f8 + ((size_t)((e * 32 + w * 4) * 32 + hc * 8)) * 64 + l;
    f16x8 wfa0 = bp2[0 * 2048], wfa1 = bp2[1 * 2048], wfa2 = bp2[2 * 2048], wfa3 = bp2[3 * 2048];
    #pragma unroll
    for (int kc2 = 0; kc2 < 8; kc2++) {
      f16x8 wfb0, wfb1, wfb2, wfb3;
      if (kc2 < 7) {
        wfb0 = bp2[0 * 2048 + (kc2 + 1) * 64];
        wfb1 = bp2[1 * 2048 + (kc2 + 1) * 64];
        wfb2 = bp2[2 * 2048 + (kc2 + 1) * 64];
        wfb3 = bp2[3 * 2048 + (kc2 + 1) * 64];
      }
      f16x8 av[4];
      #pragma unroll
      for (int mf = 0; mf < 4; mf++) {
        int row = mf * 16 + lr;
        int byte = (row * 512 + kc2 * 64 + lq * 16) ^ ((lr & 7) << 4);
        av[mf] = *(const f16x8*)((char*)h_lds + byte);
      }
      #pragma unroll
      for (int mf = 0; mf < 4; mf++) {
        acc2[mf][0] = MFMA(av[mf], wfa0, acc2[mf][0]);
        acc2[mf][1] = MFMA(av[mf], wfa1, acc2[mf][1]);
        acc2[mf][2] = MFMA(av[mf], wfa2, acc2[mf][2]);
        acc2[mf][3] = MFMA(av[mf], wfa3, acc2[mf][3]);
      }
      if (kc2 < 7) { wfa0 = wfb0; wfa1 = wfb1; wfa2 = wfb2; wfa3 = wfb3; }
    }
  }

  // bias2: cols w*64 + nf*16 + lr
  #pragma unroll
  for (int nf = 0; nf < 4; nf++) {
    float bv = b2[e * 512 + w * 64 + nf * 16 + lr];
    #pragma unroll
    for (int mf = 0; mf < 4; mf++)
      #pragma unroll
      for (int q = 0; q < 4; q++) acc2[mf][nf][q] += bv;
  }

  // ---- softmax across full row (512 cols over 8 waves) ----
  float rmax[4][4];
  #pragma unroll
  for (int mf = 0; mf < 4; mf++)
    #pragma unroll
    for (int q = 0; q < 4; q++) {
      float v = acc2[mf][0][q];
      #pragma unroll
      for (int nf = 1; nf < 4; nf++) v = fmaxf(v, acc2[mf][nf][q]);
      #pragma unroll
      for (int m = 1; m < 16; m <<= 1) v = fmaxf(v, __shfl_xor(v, m));
      rmax[mf][q] = v;
    }
  if (lr == 0) {
    #pragma unroll
    for (int mf = 0; mf < 4; mf++)
      #pragma unroll
      for (int q = 0; q < 4; q++) red[0][w][mf * 16 + lq * 4 + q] = rmax[mf][q];
  }
  __syncthreads();
  float gmax[4][4];
  #pragma unroll
  for (int mf = 0; mf < 4; mf++)
    #pragma unroll
    for (int q = 0; q < 4; q++) {
      int row = mf * 16 + lq * 4 + q;
      float v = red[0][0][row];
      #pragma unroll
      for (int ww = 1; ww < 8; ww++) v = fmaxf(v, red[0][ww][row]);
      gmax[mf][q] = v;
    }
  float psum[4][4];
  #pragma unroll
  for (int mf = 0; mf < 4; mf++)
    #pragma unroll
    for (int q = 0; q < 4; q++) psum[mf][q] = 0.f;
  #pragma unroll
  for (int mf = 0; mf < 4; mf++)
    #pragma unroll
    for (int nf = 0; nf < 4; nf++)
      #pragma unroll
      for (int q = 0; q < 4; q++) {
        float pp = __expf(acc2[mf][nf][q] - gmax[mf][q]);
        acc2[mf][nf][q] = pp;
        psum[mf][q] += pp;
      }
  #pragma unroll
  for (int mf = 0; mf < 4; mf++)
    #pragma unroll
    for (int q = 0; q < 4; q++) {
      float v = psum[mf][q];
      #pragma unroll
      for (int m = 1; m < 16; m <<= 1) v += __shfl_xor(v, m);
      psum[mf][q] = v;
    }
  if (lr == 0) {
    #pragma unroll
    for (int mf = 0; mf < 4; mf++)
      #pragma unroll
      for (int q = 0; q < 4; q++) red[1][w][mf * 16 + lq * 4 + q] = psum[mf][q];
  }
  __syncthreads();

  // ---- gated atomic accumulate into y ----
  #pragma unroll
  for (int mf = 0; mf < 4; mf++) {
    #pragma unroll
    for (int q = 0; q < 4; q++) {
      int row = mf * 16 + lq * 4 + q;
      if (row < nvalid) {
        float ssum = 0.f;
        #pragma unroll
        for (int ww = 0; ww < 8; ww++) ssum += red[1][ww][row];
        float sc = gatearr[row] / ssum;
        int orow = rowarr[row] & 0xFFFF;
        float* yr = y + (size_t)orow * 512 + w * 64 + lr;
        #pragma unroll
        for (int nf = 0; nf < 4; nf++) {
          atomicAdd(yr + nf * 16, acc2[mf][nf][q] * sc);
        }
      }
    }
  }
}

// ---------------- launch ----------------
extern "C" void kernel_launch(void* const* d_in, const int* in_sizes, int n_in,
                              void* d_out, int out_size, void* d_ws, size_t ws_size,
                              hipStream_t stream) {
  (void)in_sizes; (void)n_in; (void)out_size; (void)ws_size;
  const float* x  = (const float*)d_in[0];
  const float* wg = (const float*)d_in[1];
  const float* w1 = (const float*)d_in[2];
  const float* b1 = (const float*)d_in[3];
  const float* w2 = (const float*)d_in[4];
  const float* b2 = (const float*)d_in[5];
  float* y = (float*)d_out;

  char* ws = (char*)d_ws;
  size_t off = 0;
  auto alloc = [&](size_t bytes) -> char* {
    char* p = ws + off;
    off += (bytes + 255) & ~(size_t)255;
    return p;
  };
  f16*   w1fr       = (f16*)  alloc((size_t)16 * 512 * 1024 * 2);
  f16*   w2fr       = (f16*)  alloc((size_t)16 * 1024 * 512 * 2);
  int*   tk_idx     = (int*)  alloc((size_t)16384 * 4 * 4);
  float* tk_gate    = (float*)alloc((size_t)16384 * 4 * 4);
  int*   rows_pk    = (int*)  alloc((size_t)16 * 16384 * 4);
  float* gates_l    = (float*)alloc((size_t)16 * 16384 * 4);
  int*   partial    = (int*)  alloc(16 * 64 * 4);
  int*   chunk_base = (int*)  alloc(16 * 64 * 4);
  int*   count      = (int*)  alloc(256);
  // total ~34.6 MB

  k_cvt_w1<<<dim3(4096), dim3(256), 0, stream>>>(w1, w1fr);
  k_cvt_w2<<<dim3(4096), dim3(256), 0, stream>>>(w2, w2fr);
  k_gate<<<dim3(4096), dim3(256), 0, stream>>>(x, wg, tk_idx, tk_gate);
  k_route_count<<<dim3(1024), dim3(256), 0, stream>>>(tk_idx, partial);
  k_route_scan<<<dim3(1), dim3(64), 0, stream>>>(partial, chunk_base, count);
  k_route_scatter<<<dim3(1024), dim3(256), 0, stream>>>(tk_idx, tk_gate, chunk_base,
                                                        rows_pk, gates_l);
  k_zero<<<dim3(8192), dim3(256), 0, stream>>>((float4*)y);
  k_expert<<<dim3(4096), dim3(512), 0, stream>>>(x, w1fr, w2fr, b1, b2,
                                                 count, rows_pk, gates_l, y);
}

// Round 7
// 362.209 us; speedup vs baseline: 1.6232x; 1.2113x over previous
//
#include <hip/hip_runtime.h>
#include <hip/hip_fp16.h>

typedef _Float16 f16;
typedef _Float16 f16x8 __attribute__((ext_vector_type(8)));
typedef float f32x4 __attribute__((ext_vector_type(4)));

#define MFMA(a,b,c) __builtin_amdgcn_mfma_f32_16x16x32_f16((a),(b),(c),0,0,0)

// raw barrier: drain LDS only; leave global loads in flight (no vmcnt(0))
#define BAR() do { \
  asm volatile("s_waitcnt lgkmcnt(0)" ::: "memory"); \
  __builtin_amdgcn_sched_barrier(0); \
  __builtin_amdgcn_s_barrier(); \
  __builtin_amdgcn_sched_barrier(0); \
} while (0)

// B=16384, IN=512, HID=1024, OUT=512, E=16, K=4
// ws: w1fr 16MB + w2fr 16MB + routing ~2.6MB = ~34.6MB (known-safe)

// w1: [16][512][1024] -> fragment fid=((e*64+n0)*16+kc), lane l, elem i
//   = w1[e][kc*32+(l>>4)*8+i][n0*16+(l&15)]
__global__ void k_cvt_w1(const float* __restrict__ w1, f16* __restrict__ w1fr) {
  int fid = blockIdx.x * 4 + (threadIdx.x >> 6);
  int l = threadIdx.x & 63;
  int e = fid >> 10, n0 = (fid >> 4) & 63, kc = fid & 15;
  int kbase = kc * 32 + (l >> 4) * 8;
  int col = n0 * 16 + (l & 15);
  const float* src = w1 + ((size_t)e * 512 + kbase) * 1024 + col;
  f16x8 o;
  #pragma unroll
  for (int i = 0; i < 8; i++) o[i] = (f16)src[(size_t)i * 1024];
  *(f16x8*)(w1fr + (size_t)fid * 512 + l * 8) = o;
}

// w2: [16][1024][512] -> frag fid=((e*32+n0)*32+kc)
__global__ void k_cvt_w2(const float* __restrict__ w2, f16* __restrict__ w2fr) {
  int fid = blockIdx.x * 4 + (threadIdx.x >> 6);
  int l = threadIdx.x & 63;
  int e = fid >> 10, n0 = (fid >> 5) & 31, kc = fid & 31;
  int kbase = kc * 32 + (l >> 4) * 8;
  int col = n0 * 16 + (l & 15);
  const float* src = w2 + ((size_t)e * 1024 + kbase) * 512 + col;
  f16x8 o;
  #pragma unroll
  for (int i = 0; i < 8; i++) o[i] = (f16)src[(size_t)i * 512];
  *(f16x8*)(w2fr + (size_t)fid * 512 + l * 8) = o;
}

// ---------------- gating ----------------
__global__ void k_gate(const float* __restrict__ x, const float* __restrict__ wg,
                       int* __restrict__ tk_idx, float* __restrict__ tk_gate) {
  int w = threadIdx.x >> 6, l = threadIdx.x & 63;
  int r = blockIdx.x * 4 + w;
  float p[16];
  #pragma unroll
  for (int e = 0; e < 16; e++) p[e] = 0.f;
  const float* xr = x + (size_t)r * 512;
  #pragma unroll
  for (int t = 0; t < 8; t++) {
    float xv = xr[t * 64 + l];
    const float* wrow = wg + (t * 64 + l) * 16;
    #pragma unroll
    for (int e = 0; e < 16; e++) p[e] += xv * wrow[e];
  }
  #pragma unroll
  for (int e = 0; e < 16; e++) {
    float v = p[e];
    #pragma unroll
    for (int m = 32; m >= 1; m >>= 1) v += __shfl_xor(v, m);
    p[e] = v;
  }
  unsigned chosen = 0;
  float bv[4]; int bi[4];
  #pragma unroll
  for (int j = 0; j < 4; j++) {
    float best = -3.4e38f; int be = 0;
    #pragma unroll
    for (int e = 0; e < 16; e++) {
      bool ok = !((chosen >> e) & 1u) && (p[e] > best);
      if (ok) { best = p[e]; be = e; }
    }
    chosen |= 1u << be; bv[j] = best; bi[j] = be;
  }
  float m0 = bv[0];
  float e0 = __expf(bv[0] - m0), e1 = __expf(bv[1] - m0),
        e2 = __expf(bv[2] - m0), e3 = __expf(bv[3] - m0);
  float s = e0 + e1 + e2 + e3;
  if (l == 0) {
    *(int4*)(tk_idx + (size_t)r * 4) = make_int4(bi[0], bi[1], bi[2], bi[3]);
    *(float4*)(tk_gate + (size_t)r * 4) = make_float4(e0 / s, e1 / s, e2 / s, e3 / s);
  }
}

// ---------------- routing (deterministic compaction) ----------------
__global__ void k_route_count(const int* __restrict__ tk_idx, int* __restrict__ partial) {
  int e = blockIdx.x >> 6, chunk = blockIdx.x & 63;
  int t = threadIdx.x;
  int row = chunk * 256 + t;
  int4 tk = ((const int4*)tk_idx)[row];
  bool match = (tk.x == e) || (tk.y == e) || (tk.z == e) || (tk.w == e);
  unsigned long long m = __ballot(match);
  __shared__ int wc[4];
  if ((t & 63) == 0) wc[t >> 6] = (int)__popcll(m);
  __syncthreads();
  if (t == 0) partial[e * 64 + chunk] = wc[0] + wc[1] + wc[2] + wc[3];
}

__global__ void k_route_scan(const int* __restrict__ partial, int* __restrict__ chunk_base,
                             int* __restrict__ count) {
  int l = threadIdx.x; // 64 threads
  for (int e = 0; e < 16; e++) {
    int v = partial[e * 64 + l];
    int orig = v;
    #pragma unroll
    for (int off = 1; off < 64; off <<= 1) {
      int u = __shfl_up(v, off);
      if (l >= off) v += u;
    }
    chunk_base[e * 64 + l] = v - orig;
    if (l == 63) count[e] = v;
  }
}

__global__ void k_route_scatter(const int* __restrict__ tk_idx, const float* __restrict__ tk_gate,
                                const int* __restrict__ chunk_base, int* __restrict__ rows_pk,
                                float* __restrict__ gates_l) {
  int e = blockIdx.x >> 6, chunk = blockIdx.x & 63;
  int t = threadIdx.x, w = t >> 6, l = t & 63;
  int row = chunk * 256 + t;
  int4 tk = ((const int4*)tk_idx)[row];
  int j = (tk.x == e) ? 0 : (tk.y == e) ? 1 : (tk.z == e) ? 2 : (tk.w == e) ? 3 : -1;
  bool match = (j >= 0);
  unsigned long long m = __ballot(match);
  __shared__ int wc[4];
  if (l == 0) wc[w] = (int)__popcll(m);
  __syncthreads();
  int wbase = 0;
  #pragma unroll
  for (int i = 0; i < 4; i++) if (i < w) wbase += wc[i];
  if (match) {
    int pos = (int)__popcll(m & ((1ULL << l) - 1ULL));
    int idx = e * 16384 + chunk_base[e * 64 + chunk] + wbase + pos;
    rows_pk[idx] = row | (j << 16);
    gates_l[idx] = tk_gate[(size_t)row * 4 + j];
  }
}

// ---------------- zero output ----------------
__global__ void k_zero(float4* __restrict__ y4) {
  y4[blockIdx.x * 256 + threadIdx.x] = make_float4(0.f, 0.f, 0.f, 0.f);
}

// ---------------- fused expert FFN: BM=64, 8 waves, deep pipeline, raw barriers ----------------
// 1 block/CU regime: LDS ~104KB, VGPR budget 256. Weight fragments from global
// (L2-pinned per XCD) with cross-barrier prefetch; x double-buffered w/ T14 split.
// Padded LDS strides (272B / 1040B: 16B*(8k+1)) -> 2-way bank access (free).
__global__ __launch_bounds__(512, 2) void k_expert(
    const float* __restrict__ x, const f16* __restrict__ w1fr, const f16* __restrict__ w2fr,
    const float* __restrict__ b1, const float* __restrict__ b2,
    const int* __restrict__ count, const int* __restrict__ rows_pk,
    const float* __restrict__ gates_l, float* __restrict__ y)
{
  int p = blockIdx.x;
  int xcd = p & 7, s = p >> 3;
  int e = (xcd << 1) | (s >> 8);
  int rb = s & 255;
  int cnt = count[e];
  int mstart = rb * 64;
  if (mstart >= cnt) return;
  int nvalid = cnt - mstart; if (nvalid > 64) nvalid = 64;

  __shared__ f16 x_lds[2][64 * 136];   // stride 136 f16 = 272B; 34KB
  __shared__ f16 h_lds[64 * 520];      // stride 520 f16 = 1040B; 65KB
  __shared__ int rowarr[64];
  __shared__ float gatearr[64];
  __shared__ float red[2][8][64];      // 4KB

  int t = threadIdx.x, w = t >> 6, l = t & 63;
  int lq = l >> 4, lr = l & 15;

  if (t < 64) {
    int idx = (t < nvalid) ? t : (nvalid - 1);
    int src = e * 16384 + mstart + idx;
    rowarr[t] = rows_pk[src];
    gatearr[t] = gates_l[src];
  }
  BAR();

  // x staging assignment: 8 threads/row, 16 f32 each
  int srow = t >> 3, sc0 = (t & 7) * 16;
  const float* sp = x + (size_t)(rowarr[srow] & 0xFFFF) * 512 + sc0;
  char* xl0 = (char*)&x_lds[0][0];
  char* xl1 = (char*)&x_lds[1][0];
  char* hl  = (char*)h_lds;
  int xwb = srow * 272 + sc0 * 2;      // byte offset of this thread's x write

  const f16x8* w1f8 = (const f16x8*)w1fr;
  const f16x8* w2f8 = (const f16x8*)w2fr;

  f32x4 acc2[4][4];   // rows mf*16+lq*4+q, cols w*64+nf*16+lr
  #pragma unroll
  for (int a = 0; a < 4; a++)
    #pragma unroll
    for (int b = 0; b < 4; b++)
      #pragma unroll
      for (int q = 0; q < 4; q++) acc2[a][b][q] = 0.f;

  #pragma unroll 1
  for (int hc = 0; hc < 2; hc++) {
    // ---- x prologue: stage chunk 0 -> buf 0; preload kk=0 weights ----
    {
      const float* qp = sp;  // chunk 0
      float4 u0 = ((const float4*)qp)[0], u1 = ((const float4*)qp)[1];
      float4 u2 = ((const float4*)qp)[2], u3 = ((const float4*)qp)[3];
      f16x8 v0, v1;
      v0[0]=(f16)u0.x; v0[1]=(f16)u0.y; v0[2]=(f16)u0.z; v0[3]=(f16)u0.w;
      v0[4]=(f16)u1.x; v0[5]=(f16)u1.y; v0[6]=(f16)u1.z; v0[7]=(f16)u1.w;
      v1[0]=(f16)u2.x; v1[1]=(f16)u2.y; v1[2]=(f16)u2.z; v1[3]=(f16)u2.w;
      v1[4]=(f16)u3.x; v1[5]=(f16)u3.y; v1[6]=(f16)u3.z; v1[7]=(f16)u3.w;
      *(f16x8*)(xl0 + xwb) = v0;
      *(f16x8*)(xl0 + xwb + 16) = v1;
    }
    // w1 frag base: n0g = hc*32 + w*4 + nf ; kcg = kk*4 + k4
    // fid=(e*64+n0g)*16+kcg ; n0 stride = 16*64 f16x8, kc stride = 64
    const f16x8* bp1h = w1f8 + ((size_t)((e * 64 + hc * 32 + w * 4) * 16)) * 64 + l;
    f16x8 ba0 = bp1h[0], ba1 = bp1h[16 * 64], ba2 = bp1h[32 * 64], ba3 = bp1h[48 * 64];
    BAR();

    f32x4 acc1[4][4];  // rows mf*16+lq*4+q, h-cols w*64+nf*16+lr (of this 512 chunk)
    #pragma unroll
    for (int a = 0; a < 4; a++)
      #pragma unroll
      for (int b = 0; b < 4; b++)
        #pragma unroll
        for (int q = 0; q < 4; q++) acc1[a][b][q] = 0.f;

    #pragma unroll 1
    for (int kk = 0; kk < 4; kk++) {
      char* xbuf = (kk & 1) ? xl1 : xl0;
      char* xnxt = (kk & 1) ? xl0 : xl1;
      // T14: issue next x chunk loads now (consumed after MFMA)
      float4 u0, u1, u2, u3;
      if (kk < 3) {
        const float* qp = sp + (kk + 1) * 128;
        u0 = ((const float4*)qp)[0]; u1 = ((const float4*)qp)[1];
        u2 = ((const float4*)qp)[2]; u3 = ((const float4*)qp)[3];
      }
      const f16x8* bp1 = bp1h + (size_t)(kk * 4) * 64;
      #pragma unroll
      for (int k4 = 0; k4 < 4; k4++) {
        f16x8 bb0, bb1, bb2, bb3;
        if (k4 < 3) {
          bb0 = bp1[(k4 + 1) * 64];
          bb1 = bp1[16 * 64 + (k4 + 1) * 64];
          bb2 = bp1[32 * 64 + (k4 + 1) * 64];
          bb3 = bp1[48 * 64 + (k4 + 1) * 64];
        }
        f16x8 av[4];
        #pragma unroll
        for (int mf = 0; mf < 4; mf++)
          av[mf] = *(const f16x8*)(xbuf + (mf * 16 + lr) * 272 + k4 * 64 + lq * 16);
        #pragma unroll
        for (int mf = 0; mf < 4; mf++) {
          acc1[mf][0] = MFMA(av[mf], ba0, acc1[mf][0]);
          acc1[mf][1] = MFMA(av[mf], ba1, acc1[mf][1]);
          acc1[mf][2] = MFMA(av[mf], ba2, acc1[mf][2]);
          acc1[mf][3] = MFMA(av[mf], ba3, acc1[mf][3]);
        }
        if (k4 < 3) { ba0 = bb0; ba1 = bb1; ba2 = bb2; ba3 = bb3; }
      }
      if (kk < 3) {
        // write next x chunk (dbuf; current buf readers unaffected)
        f16x8 v0, v1;
        v0[0]=(f16)u0.x; v0[1]=(f16)u0.y; v0[2]=(f16)u0.z; v0[3]=(f16)u0.w;
        v0[4]=(f16)u1.x; v0[5]=(f16)u1.y; v0[6]=(f16)u1.z; v0[7]=(f16)u1.w;
        v1[0]=(f16)u2.x; v1[1]=(f16)u2.y; v1[2]=(f16)u2.z; v1[3]=(f16)u2.w;
        v1[4]=(f16)u3.x; v1[5]=(f16)u3.y; v1[6]=(f16)u3.z; v1[7]=(f16)u3.w;
        *(f16x8*)(xnxt + xwb) = v0;
        *(f16x8*)(xnxt + xwb + 16) = v1;
        // cross-barrier weight prefetch for kk+1
        const f16x8* bpn = bp1h + (size_t)((kk + 1) * 4) * 64;
        ba0 = bpn[0]; ba1 = bpn[16 * 64]; ba2 = bpn[32 * 64]; ba3 = bpn[48 * 64];
      }
      BAR();
    }

    // ---- h epilogue: bias + relu -> h_lds ----
    #pragma unroll
    for (int nf = 0; nf < 4; nf++) {
      int colc = w * 64 + nf * 16 + lr;
      float bv = b1[e * 1024 + hc * 512 + colc];
      #pragma unroll
      for (int mf = 0; mf < 4; mf++)
        #pragma unroll
        for (int q = 0; q < 4; q++) {
          int row = mf * 16 + lq * 4 + q;
          float hv = fmaxf(acc1[mf][nf][q] + bv, 0.f);
          *(f16*)(hl + row * 1040 + colc * 2) = (f16)hv;
        }
    }
    // preload stage-2 weights (kc2=0) before the barrier
    // fid2=(e*32 + w*4+nf)*32 + hc*16+kc2 ; nf stride = 32*64, kc2 stride = 64
    const f16x8* bp2 = w2f8 + ((size_t)((e * 32 + w * 4) * 32 + hc * 16)) * 64 + l;
    f16x8 wa0 = bp2[0], wa1 = bp2[32 * 64], wa2 = bp2[64 * 64], wa3 = bp2[96 * 64];
    BAR();

    // ---- stage 2: acc2 += h_chunk @ w2, K=512 (16 steps of 32) ----
    #pragma unroll 2
    for (int kc2 = 0; kc2 < 16; kc2++) {
      f16x8 wb0, wb1, wb2, wb3;
      if (kc2 < 15) {
        wb0 = bp2[(kc2 + 1) * 64];
        wb1 = bp2[32 * 64 + (kc2 + 1) * 64];
        wb2 = bp2[64 * 64 + (kc2 + 1) * 64];
        wb3 = bp2[96 * 64 + (kc2 + 1) * 64];
      }
      f16x8 av[4];
      #pragma unroll
      for (int mf = 0; mf < 4; mf++)
        av[mf] = *(const f16x8*)(hl + (mf * 16 + lr) * 1040 + kc2 * 64 + lq * 16);
      #pragma unroll
      for (int mf = 0; mf < 4; mf++) {
        acc2[mf][0] = MFMA(av[mf], wa0, acc2[mf][0]);
        acc2[mf][1] = MFMA(av[mf], wa1, acc2[mf][1]);
        acc2[mf][2] = MFMA(av[mf], wa2, acc2[mf][2]);
        acc2[mf][3] = MFMA(av[mf], wa3, acc2[mf][3]);
      }
      if (kc2 < 15) { wa0 = wb0; wa1 = wb1; wa2 = wb2; wa3 = wb3; }
    }
    // no barrier needed here: next hc's x writes hit x_lds (disjoint) and its
    // kk barriers order h reuse; each wave drains lgkm at its next BAR.
  }

  // bias2: cols w*64 + nf*16 + lr
  #pragma unroll
  for (int nf = 0; nf < 4; nf++) {
    float bv = b2[e * 512 + w * 64 + nf * 16 + lr];
    #pragma unroll
    for (int mf = 0; mf < 4; mf++)
      #pragma unroll
      for (int q = 0; q < 4; q++) acc2[mf][nf][q] += bv;
  }

  // ---- softmax across full row (512 cols over 8 waves) ----
  float rmax[4][4];
  #pragma unroll
  for (int mf = 0; mf < 4; mf++)
    #pragma unroll
    for (int q = 0; q < 4; q++) {
      float v = acc2[mf][0][q];
      #pragma unroll
      for (int nf = 1; nf < 4; nf++) v = fmaxf(v, acc2[mf][nf][q]);
      #pragma unroll
      for (int m = 1; m < 16; m <<= 1) v = fmaxf(v, __shfl_xor(v, m));
      rmax[mf][q] = v;
    }
  if (lr == 0) {
    #pragma unroll
    for (int mf = 0; mf < 4; mf++)
      #pragma unroll
      for (int q = 0; q < 4; q++) red[0][w][mf * 16 + lq * 4 + q] = rmax[mf][q];
  }
  BAR();
  float gmax[4][4];
  #pragma unroll
  for (int mf = 0; mf < 4; mf++)
    #pragma unroll
    for (int q = 0; q < 4; q++) {
      int row = mf * 16 + lq * 4 + q;
      float v = red[0][0][row];
      #pragma unroll
      for (int ww = 1; ww < 8; ww++) v = fmaxf(v, red[0][ww][row]);
      gmax[mf][q] = v;
    }
  float psum[4][4];
  #pragma unroll
  for (int mf = 0; mf < 4; mf++)
    #pragma unroll
    for (int q = 0; q < 4; q++) psum[mf][q] = 0.f;
  #pragma unroll
  for (int mf = 0; mf < 4; mf++)
    #pragma unroll
    for (int nf = 0; nf < 4; nf++)
      #pragma unroll
      for (int q = 0; q < 4; q++) {
        float pp = __expf(acc2[mf][nf][q] - gmax[mf][q]);
        acc2[mf][nf][q] = pp;
        psum[mf][q] += pp;
      }
  #pragma unroll
  for (int mf = 0; mf < 4; mf++)
    #pragma unroll
    for (int q = 0; q < 4; q++) {
      float v = psum[mf][q];
      #pragma unroll
      for (int m = 1; m < 16; m <<= 1) v += __shfl_xor(v, m);
      psum[mf][q] = v;
    }
  if (lr == 0) {
    #pragma unroll
    for (int mf = 0; mf < 4; mf++)
      #pragma unroll
      for (int q = 0; q < 4; q++) red[1][w][mf * 16 + lq * 4 + q] = psum[mf][q];
  }
  BAR();

  // ---- gated atomic accumulate into y ----
  #pragma unroll
  for (int mf = 0; mf < 4; mf++) {
    #pragma unroll
    for (int q = 0; q < 4; q++) {
      int row = mf * 16 + lq * 4 + q;
      if (row < nvalid) {
        float ssum = 0.f;
        #pragma unroll
        for (int ww = 0; ww < 8; ww++) ssum += red[1][ww][row];
        float sc = gatearr[row] / ssum;
        int orow = rowarr[row] & 0xFFFF;
        float* yr = y + (size_t)orow * 512 + w * 64 + lr;
        #pragma unroll
        for (int nf = 0; nf < 4; nf++) {
          atomicAdd(yr + nf * 16, acc2[mf][nf][q] * sc);
        }
      }
    }
  }
}

// ---------------- launch ----------------
extern "C" void kernel_launch(void* const* d_in, const int* in_sizes, int n_in,
                              void* d_out, int out_size, void* d_ws, size_t ws_size,
                              hipStream_t stream) {
  (void)in_sizes; (void)n_in; (void)out_size; (void)ws_size;
  const float* x  = (const float*)d_in[0];
  const float* wg = (const float*)d_in[1];
  const float* w1 = (const float*)d_in[2];
  const float* b1 = (const float*)d_in[3];
  const float* w2 = (const float*)d_in[4];
  const float* b2 = (const float*)d_in[5];
  float* y = (float*)d_out;

  char* ws = (char*)d_ws;
  size_t off = 0;
  auto alloc = [&](size_t bytes) -> char* {
    char* p = ws + off;
    off += (bytes + 255) & ~(size_t)255;
    return p;
  };
  f16*   w1fr       = (f16*)  alloc((size_t)16 * 512 * 1024 * 2);
  f16*   w2fr       = (f16*)  alloc((size_t)16 * 1024 * 512 * 2);
  int*   tk_idx     = (int*)  alloc((size_t)16384 * 4 * 4);
  float* tk_gate    = (float*)alloc((size_t)16384 * 4 * 4);
  int*   rows_pk    = (int*)  alloc((size_t)16 * 16384 * 4);
  float* gates_l    = (float*)alloc((size_t)16 * 16384 * 4);
  int*   partial    = (int*)  alloc(16 * 64 * 4);
  int*   chunk_base = (int*)  alloc(16 * 64 * 4);
  int*   count      = (int*)  alloc(256);
  // total ~34.6 MB

  k_cvt_w1<<<dim3(4096), dim3(256), 0, stream>>>(w1, w1fr);
  k_cvt_w2<<<dim3(4096), dim3(256), 0, stream>>>(w2, w2fr);
  k_gate<<<dim3(4096), dim3(256), 0, stream>>>(x, wg, tk_idx, tk_gate);
  k_route_count<<<dim3(1024), dim3(256), 0, stream>>>(tk_idx, partial);
  k_route_scan<<<dim3(1), dim3(64), 0, stream>>>(partial, chunk_base, count);
  k_route_scatter<<<dim3(1024), dim3(256), 0, stream>>>(tk_idx, tk_gate, chunk_base,
                                                        rows_pk, gates_l);
  k_zero<<<dim3(8192), dim3(256), 0, stream>>>((float4*)y);
  k_expert<<<dim3(4096), dim3(512), 0, stream>>>(x, w1fr, w2fr, b1, b2,
                                                 count, rows_pk, gates_l, y);
}